// Round 2
// baseline (541.100 us; speedup 1.0000x reference)
//
#include <hip/hip_runtime.h>
#include <math.h>

#define BATCH 32
#define NH 32
#define NKVH 8
#define GRP 4
#define HD 128
#define BLKSZ 16
#define MAXB 128
#define PART 256
#define NPART 8
#define SCALE 0.08838834764831845f
#define NEGINF (-1e30f)

// ws layout (float elements):
#define WS_ML 0                                   // B*KVH*G*NPART*2 = 16384
#define WS_OP (BATCH*NKVH*GRP*NPART*2)            // +B*KVH*G*NPART*D = 1048576

__global__ __launch_bounds__(256)
void attn_fused(const float* __restrict__ q,
                const float* __restrict__ nk,
                const float* __restrict__ nv,
                const float* __restrict__ kc,
                const float* __restrict__ vc,
                const int* __restrict__ btab,
                const int* __restrict__ ctx,
                float* __restrict__ ws)
{
    int part = blockIdx.x, kvh = blockIdx.y, b = blockIdx.z;
    int L = ctx[b];
    int start = part * PART;
    if (start >= L) return;                  // reducer skips unwritten partitions
    int end = min(start + PART, L);
    int n = end - start;
    int tok = L - 1;                         // new-token slot: read roped nk / raw nv

    int tid = threadIdx.x;
    int hw = tid >> 5;                       // half-wave 0..7 (token lane-group)
    int hl = tid & 31;                       // lane in half-wave: d = 4*hl..4*hl+3
    int wave = tid >> 6, lane = tid & 63;

    __shared__ float cs[64], sn[64];
    __shared__ float qs[GRP][HD];            // roped q, 2 KB
    __shared__ float ks[HD];                 // roped new-k
    __shared__ float sc[GRP][PART];          // scores -> probs, 4 KB
    __shared__ float oacc[8][GRP][HD];       // half-wave partial outputs, 16 KB

    // ---- RoPE tables (double for accuracy; once per block, negligible) ----
    if (tid < 64) {
        double f = pow(10000.0, -(double)tid / 64.0);
        double a = (double)L * f;            // pos = context_lens per reference
        cs[tid] = (float)cos(a);
        sn[tid] = (float)sin(a);
    }
    __syncthreads();

    // ---- rope q (4 heads) and new-k into LDS ----
    {
        int g = tid >> 6, d = tid & 63;
        const float* qp = q + ((size_t)b * NH + kvh * GRP + g) * HD;
        float x = qp[d], y = qp[d + 64];
        float c = cs[d], s = sn[d];
        qs[g][d]      = x * c - y * s;
        qs[g][d + 64] = y * c + x * s;
    }
    if (tok >= start && tok < end && tid < 64) {
        int d = tid;
        const float* kp = nk + ((size_t)b * NKVH + kvh) * HD;
        float x = kp[d], y = kp[d + 64];
        float c = cs[d], s = sn[d];
        ks[d]      = x * c - y * s;
        ks[d + 64] = y * c + x * s;
    }
    __syncthreads();

    float4 qa[GRP];
#pragma unroll
    for (int g = 0; g < GRP; ++g)
        qa[g] = *(const float4*)(&qs[g][4 * hl]);

    const int* bt = btab + b * MAXB;

    // ---- Phase 1: scores, 2 tokens in flight per half-wave ----
    for (int s = start + hw; s < end; s += 16) {
        int s1 = s + 8;
        bool h1 = (s1 < end);
        float4 k0, k1 = make_float4(0.f, 0.f, 0.f, 0.f);
        if (s == tok) {
            k0 = *(const float4*)(&ks[4 * hl]);
        } else {
            int blk = bt[s >> 4];
            k0 = *(const float4*)(kc + (((size_t)blk * BLKSZ + (s & 15)) * NKVH + kvh) * HD + 4 * hl);
        }
        if (h1) {
            if (s1 == tok) {
                k1 = *(const float4*)(&ks[4 * hl]);
            } else {
                int blk = bt[s1 >> 4];
                k1 = *(const float4*)(kc + (((size_t)blk * BLKSZ + (s1 & 15)) * NKVH + kvh) * HD + 4 * hl);
            }
        }
        float p0[GRP], p1[GRP];
#pragma unroll
        for (int g = 0; g < GRP; ++g) {
            p0[g] = qa[g].x * k0.x + qa[g].y * k0.y + qa[g].z * k0.z + qa[g].w * k0.w;
            p1[g] = qa[g].x * k1.x + qa[g].y * k1.y + qa[g].z * k1.z + qa[g].w * k1.w;
        }
#pragma unroll
        for (int off = 16; off >= 1; off >>= 1) {
#pragma unroll
            for (int g = 0; g < GRP; ++g) {
                p0[g] += __shfl_xor(p0[g], off, 32);
                p1[g] += __shfl_xor(p1[g], off, 32);
            }
        }
        if (hl == 0) {
#pragma unroll
            for (int g = 0; g < GRP; ++g) {
                sc[g][s - start] = p0[g] * SCALE;
                if (h1) sc[g][s1 - start] = p1[g] * SCALE;
            }
        }
    }
    __syncthreads();

    // ---- Phase 2: per-head softmax (unnormalized), wave w owns head w ----
    {
        int g = wave;
        float m = NEGINF;
        for (int i = lane; i < n; i += 64) m = fmaxf(m, sc[g][i]);
#pragma unroll
        for (int off = 32; off >= 1; off >>= 1) m = fmaxf(m, __shfl_xor(m, off));
        float sum = 0.f;
        for (int i = lane; i < n; i += 64) {
            float e = __expf(sc[g][i] - m);
            sc[g][i] = e;
            sum += e;
        }
#pragma unroll
        for (int off = 32; off >= 1; off >>= 1) sum += __shfl_xor(sum, off);
        if (lane == 0) {
            size_t mlidx = ((((size_t)b * NKVH + kvh) * GRP + g) * NPART + part) * 2;
            ws[WS_ML + mlidx]     = m;
            ws[WS_ML + mlidx + 1] = sum;
        }
    }
    __syncthreads();

    // ---- Phase 3: o = sum_s p[s] * V[s], 2 tokens in flight ----
    float4 acc[GRP];
#pragma unroll
    for (int g = 0; g < GRP; ++g) acc[g] = make_float4(0.f, 0.f, 0.f, 0.f);

    for (int s = start + hw; s < end; s += 16) {
        int s1 = s + 8;
        bool h1 = (s1 < end);
        float4 v0, v1 = make_float4(0.f, 0.f, 0.f, 0.f);
        if (s == tok) {
            v0 = *(const float4*)(nv + ((size_t)b * NKVH + kvh) * HD + 4 * hl);
        } else {
            int blk = bt[s >> 4];
            v0 = *(const float4*)(vc + (((size_t)blk * BLKSZ + (s & 15)) * NKVH + kvh) * HD + 4 * hl);
        }
        if (h1) {
            if (s1 == tok) {
                v1 = *(const float4*)(nv + ((size_t)b * NKVH + kvh) * HD + 4 * hl);
            } else {
                int blk = bt[s1 >> 4];
                v1 = *(const float4*)(vc + (((size_t)blk * BLKSZ + (s1 & 15)) * NKVH + kvh) * HD + 4 * hl);
            }
        }
        int i0 = s - start, i1 = s1 - start;
#pragma unroll
        for (int g = 0; g < GRP; ++g) {
            float e0 = sc[g][i0];
            acc[g].x += e0 * v0.x; acc[g].y += e0 * v0.y;
            acc[g].z += e0 * v0.z; acc[g].w += e0 * v0.w;
        }
        if (h1) {
#pragma unroll
            for (int g = 0; g < GRP; ++g) {
                float e1 = sc[g][i1];
                acc[g].x += e1 * v1.x; acc[g].y += e1 * v1.y;
                acc[g].z += e1 * v1.z; acc[g].w += e1 * v1.w;
            }
        }
    }
#pragma unroll
    for (int g = 0; g < GRP; ++g)
        *(float4*)&oacc[hw][g][4 * hl] = acc[g];
    __syncthreads();

    for (int o = tid; o < GRP * HD; o += 256) {
        int g = o >> 7, d = o & 127;
        float ssum = 0.f;
#pragma unroll
        for (int w = 0; w < 8; ++w) ssum += oacc[w][g][d];
        ws[WS_OP + ((((size_t)b * NKVH + kvh) * GRP + g) * NPART + part) * HD + d] = ssum;
    }
}

__global__ __launch_bounds__(128)
void attn_reduce(const int* __restrict__ ctx,
                 const float* __restrict__ ws,
                 float* __restrict__ out) {
    int bh = blockIdx.x;
    int b = bh >> 5;
    int h = bh & 31;
    int kvh = h >> 2, g = h & 3;
    int L = ctx[b];
    int np = min(NPART, (L + PART - 1) / PART);
    size_t base = (((size_t)b * NKVH + kvh) * GRP + g) * NPART;
    float M = NEGINF;
    for (int p = 0; p < np; ++p)
        M = fmaxf(M, ws[WS_ML + (base + p) * 2]);
    float w_[NPART];
    float Lsum = 0.f;
    for (int p = 0; p < np; ++p) {
        float e = __expf(ws[WS_ML + (base + p) * 2] - M);
        w_[p] = e;
        Lsum += e * ws[WS_ML + (base + p) * 2 + 1];
    }
    float inv = 1.0f / Lsum;
    int d = threadIdx.x;
    float acc = 0.f;
    for (int p = 0; p < np; ++p)
        acc += w_[p] * ws[WS_OP + (base + p) * HD + d];
    out[((size_t)b * NH + h) * HD + d] = acc * inv;
}

extern "C" void kernel_launch(void* const* d_in, const int* in_sizes, int n_in,
                              void* d_out, int out_size, void* d_ws, size_t ws_size,
                              hipStream_t stream) {
    const float* q    = (const float*)d_in[0];
    const float* nk   = (const float*)d_in[1];
    const float* nv   = (const float*)d_in[2];
    const float* kc   = (const float*)d_in[3];
    const float* vc   = (const float*)d_in[4];
    const int*   btab = (const int*)d_in[5];
    const int*   ctx  = (const int*)d_in[6];
    float* out = (float*)d_out;
    float* ws  = (float*)d_ws;

    attn_fused<<<dim3(NPART, NKVH, BATCH), dim3(256), 0, stream>>>(q, nk, nv, kc, vc, btab, ctx, ws);
    attn_reduce<<<dim3(BATCH * NH), dim3(128), 0, stream>>>(ctx, ws, out);
}

// Round 3
// 489.569 us; speedup vs baseline: 1.1053x; 1.1053x over previous
//
#include <hip/hip_runtime.h>
#include <math.h>

#define BATCH 32
#define NH 32
#define NKVH 8
#define GRP 4
#define HD 128
#define BLKSZ 16
#define MAXB 128
#define PART 128
#define NPART 16
#define SCALE 0.08838834764831845f
#define NEGINF (-1e30f)

// ws layout (float elements):
#define WS_QROT 0                                    // B*NH*HD = 131072 (q roped, pre-scaled)
#define WS_ML   (BATCH*NH*HD)                        // +B*KVH*G*NPART*2 = 32768
#define WS_OP   (WS_ML + BATCH*NKVH*GRP*NPART*2)     // +B*KVH*G*NPART*HD = 2097152

// ---- prep: rope q -> ws (pre-scaled), rope new-k & copy new-v into caches ----
__global__ __launch_bounds__(128)
void prep(const float* __restrict__ q,
          const float* __restrict__ nk,
          const float* __restrict__ nv,
          float* __restrict__ kc,
          float* __restrict__ vc,
          const int* __restrict__ btab,
          const int* __restrict__ ctx,
          float* __restrict__ ws) {
    int b = blockIdx.x;
    int t = threadIdx.x;                 // 0..127, covers d
    int L = ctx[b];
    __shared__ float cs[64], sn[64];
    if (t < 64) {
        double f = pow(10000.0, -(double)t / 64.0);
        double a = (double)L * f;        // pos = context_lens per reference
        cs[t] = (float)cos(a);
        sn[t] = (float)sin(a);
    }
    __syncthreads();
    float c = cs[t & 63], s = sn[t & 63];
    for (int h = 0; h < NH; ++h) {
        const float* qp = q + ((size_t)b * NH + h) * HD;
        float x = qp[t], y = qp[t ^ 64];
        float r = (t < 64) ? (x * c - y * s) : (x * c + y * s);
        ws[WS_QROT + ((size_t)b * NH + h) * HD + t] = r * SCALE;
    }
    int tok = L - 1;
    int blk = btab[b * MAXB + (tok >> 4)];
    int off = tok & 15;
    for (int kh = 0; kh < NKVH; ++kh) {
        const float* kp = nk + ((size_t)b * NKVH + kh) * HD;
        float x = kp[t], y = kp[t ^ 64];
        float r = (t < 64) ? (x * c - y * s) : (x * c + y * s);
        size_t row = (((size_t)blk * BLKSZ + off) * NKVH + kh) * HD;
        kc[row + t] = r;
        vc[row + t] = nv[((size_t)b * NKVH + kh) * HD + t];
    }
}

// ---- attn: clean streaming flash-decode partial ----
__global__ __launch_bounds__(256)
void attn(const float* __restrict__ kc,
          const float* __restrict__ vc,
          const int* __restrict__ ctx,
          const int* __restrict__ btab,
          float* __restrict__ ws)
{
    int part = blockIdx.x, kvh = blockIdx.y, b = blockIdx.z;
    int L = ctx[b];
    int start = part * PART;
    if (start >= L) return;              // reducer skips unwritten partitions
    int end = min(start + PART, L);
    int n = end - start;

    int tid = threadIdx.x;
    int hw = tid >> 5;                   // half-wave 0..7
    int hl = tid & 31;                   // lane in half-wave: d = 4*hl..4*hl+3
    int wave = tid >> 6, lane = tid & 63;

    __shared__ int   bts[PART / BLKSZ];  // 8 block ids
    __shared__ float qs[GRP][HD];        // roped+scaled q, 2 KB
    __shared__ float sc[GRP][PART];      // scores -> probs, 2 KB
    __shared__ float oacc[4][GRP][HD];   // per-wave partial outputs, 8 KB

    if (tid < PART / BLKSZ)
        bts[tid] = btab[b * MAXB + (start >> 4) + tid];
    {   // 512 floats, 256 threads x float2
        const float* qrot = ws + WS_QROT + ((size_t)b * NH + kvh * GRP) * HD;
        ((float2*)&qs[0][0])[tid] = ((const float2*)qrot)[tid];
    }
    __syncthreads();

    float4 qa[GRP];
#pragma unroll
    for (int g = 0; g < GRP; ++g)
        qa[g] = *(const float4*)(&qs[g][4 * hl]);

    const size_t koff = (size_t)kvh * HD + 4 * hl;

    // ---- Phase 1: scores; 4 tokens (4 x 512B loads) in flight per half-wave ----
    int i = start + hw;
    for (; i + 24 < end; i += 32) {
        int s0 = i, s1 = i + 8, s2 = i + 16, s3 = i + 24;
        float4 k0 = *(const float4*)(kc + ((size_t)bts[(s0 - start) >> 4] << 14) + ((s0 & 15) << 10) + koff);
        float4 k1 = *(const float4*)(kc + ((size_t)bts[(s1 - start) >> 4] << 14) + ((s1 & 15) << 10) + koff);
        float4 k2 = *(const float4*)(kc + ((size_t)bts[(s2 - start) >> 4] << 14) + ((s2 & 15) << 10) + koff);
        float4 k3 = *(const float4*)(kc + ((size_t)bts[(s3 - start) >> 4] << 14) + ((s3 & 15) << 10) + koff);
        float p0[GRP], p1[GRP], p2[GRP], p3[GRP];
#pragma unroll
        for (int g = 0; g < GRP; ++g) {
            p0[g] = qa[g].x * k0.x + qa[g].y * k0.y + qa[g].z * k0.z + qa[g].w * k0.w;
            p1[g] = qa[g].x * k1.x + qa[g].y * k1.y + qa[g].z * k1.z + qa[g].w * k1.w;
            p2[g] = qa[g].x * k2.x + qa[g].y * k2.y + qa[g].z * k2.z + qa[g].w * k2.w;
            p3[g] = qa[g].x * k3.x + qa[g].y * k3.y + qa[g].z * k3.z + qa[g].w * k3.w;
        }
#pragma unroll
        for (int off = 16; off >= 1; off >>= 1) {
#pragma unroll
            for (int g = 0; g < GRP; ++g) {
                p0[g] += __shfl_xor(p0[g], off, 32);
                p1[g] += __shfl_xor(p1[g], off, 32);
                p2[g] += __shfl_xor(p2[g], off, 32);
                p3[g] += __shfl_xor(p3[g], off, 32);
            }
        }
        if (hl == 0) {
#pragma unroll
            for (int g = 0; g < GRP; ++g) {
                sc[g][s0 - start] = p0[g];
                sc[g][s1 - start] = p1[g];
                sc[g][s2 - start] = p2[g];
                sc[g][s3 - start] = p3[g];
            }
        }
    }
    for (; i < end; i += 8) {
        float4 k0 = *(const float4*)(kc + ((size_t)bts[(i - start) >> 4] << 14) + ((i & 15) << 10) + koff);
        float p0[GRP];
#pragma unroll
        for (int g = 0; g < GRP; ++g)
            p0[g] = qa[g].x * k0.x + qa[g].y * k0.y + qa[g].z * k0.z + qa[g].w * k0.w;
#pragma unroll
        for (int off = 16; off >= 1; off >>= 1)
#pragma unroll
            for (int g = 0; g < GRP; ++g)
                p0[g] += __shfl_xor(p0[g], off, 32);
        if (hl == 0)
#pragma unroll
            for (int g = 0; g < GRP; ++g)
                sc[g][i - start] = p0[g];
    }
    __syncthreads();

    // ---- Phase 2: per-head softmax (unnormalized), wave w owns head w ----
    {
        int g = wave;
        float m = NEGINF;
        for (int j = lane; j < n; j += 64) m = fmaxf(m, sc[g][j]);
#pragma unroll
        for (int off = 32; off >= 1; off >>= 1) m = fmaxf(m, __shfl_xor(m, off));
        float sum = 0.f;
        for (int j = lane; j < n; j += 64) {
            float e = __expf(sc[g][j] - m);
            sc[g][j] = e;
            sum += e;
        }
#pragma unroll
        for (int off = 32; off >= 1; off >>= 1) sum += __shfl_xor(sum, off);
        if (lane == 0) {
            size_t mlidx = ((((size_t)b * NKVH + kvh) * GRP + g) * NPART + part) * 2;
            ws[WS_ML + mlidx]     = m;
            ws[WS_ML + mlidx + 1] = sum;
        }
    }
    __syncthreads();

    // ---- Phase 3: o += p[s]*V[s]; wave owns a contiguous 64-token chunk,
    //      float2 per lane, 4 x 512B loads in flight ----
    float2 acc[GRP];
#pragma unroll
    for (int g = 0; g < GRP; ++g) acc[g] = make_float2(0.f, 0.f);

    const size_t voff = (size_t)kvh * HD + 2 * lane;
    int t0 = start + (wave << 6);
    int tend = min(t0 + 64, end);
    int t = t0;
    for (; t + 3 < tend; t += 4) {
        float2 v0 = *(const float2*)(vc + ((size_t)bts[(t     - start) >> 4] << 14) + (( t      & 15) << 10) + voff);
        float2 v1 = *(const float2*)(vc + ((size_t)bts[(t + 1 - start) >> 4] << 14) + (((t + 1) & 15) << 10) + voff);
        float2 v2 = *(const float2*)(vc + ((size_t)bts[(t + 2 - start) >> 4] << 14) + (((t + 2) & 15) << 10) + voff);
        float2 v3 = *(const float2*)(vc + ((size_t)bts[(t + 3 - start) >> 4] << 14) + (((t + 3) & 15) << 10) + voff);
#pragma unroll
        for (int g = 0; g < GRP; ++g) {
            float4 e = *(const float4*)(&sc[g][t - start]);   // (t-start) % 4 == 0
            acc[g].x += e.x * v0.x; acc[g].y += e.x * v0.y;
            acc[g].x += e.y * v1.x; acc[g].y += e.y * v1.y;
            acc[g].x += e.z * v2.x; acc[g].y += e.z * v2.y;
            acc[g].x += e.w * v3.x; acc[g].y += e.w * v3.y;
        }
    }
    for (; t < tend; ++t) {
        float2 v0 = *(const float2*)(vc + ((size_t)bts[(t - start) >> 4] << 14) + ((t & 15) << 10) + voff);
#pragma unroll
        for (int g = 0; g < GRP; ++g) {
            float e = sc[g][t - start];
            acc[g].x += e * v0.x; acc[g].y += e * v0.y;
        }
    }
#pragma unroll
    for (int g = 0; g < GRP; ++g)
        *(float2*)&oacc[wave][g][2 * lane] = acc[g];
    __syncthreads();

    for (int o = tid; o < GRP * HD; o += 256) {
        int g = o >> 7, d = o & 127;
        float ssum = oacc[0][g][d] + oacc[1][g][d] + oacc[2][g][d] + oacc[3][g][d];
        ws[WS_OP + ((((size_t)b * NKVH + kvh) * GRP + g) * NPART + part) * HD + d] = ssum;
    }
}

__global__ __launch_bounds__(128)
void attn_reduce(const int* __restrict__ ctx,
                 const float* __restrict__ ws,
                 float* __restrict__ out) {
    int bh = blockIdx.x;
    int b = bh >> 5;
    int h = bh & 31;
    int kvh = h >> 2, g = h & 3;
    int L = ctx[b];
    int np = min(NPART, (L + PART - 1) / PART);
    size_t base = (((size_t)b * NKVH + kvh) * GRP + g) * NPART;
    float M = NEGINF;
    for (int p = 0; p < np; ++p)
        M = fmaxf(M, ws[WS_ML + (base + p) * 2]);
    float w_[NPART];
    float Lsum = 0.f;
    for (int p = 0; p < np; ++p) {
        float e = __expf(ws[WS_ML + (base + p) * 2] - M);
        w_[p] = e;
        Lsum += e * ws[WS_ML + (base + p) * 2 + 1];
    }
    float inv = 1.0f / Lsum;
    int d = threadIdx.x;
    float acc = 0.f;
    for (int p = 0; p < np; ++p)
        acc += w_[p] * ws[WS_OP + (base + p) * HD + d];
    out[((size_t)b * NH + h) * HD + d] = acc * inv;
}

extern "C" void kernel_launch(void* const* d_in, const int* in_sizes, int n_in,
                              void* d_out, int out_size, void* d_ws, size_t ws_size,
                              hipStream_t stream) {
    const float* q    = (const float*)d_in[0];
    const float* nk   = (const float*)d_in[1];
    const float* nv   = (const float*)d_in[2];
    float*       kc   = (float*)d_in[3];   // mutated like the reference; harness restores pre-launch
    float*       vc   = (float*)d_in[4];
    const int*   btab = (const int*)d_in[5];
    const int*   ctx  = (const int*)d_in[6];
    float* out = (float*)d_out;
    float* ws  = (float*)d_ws;

    prep<<<dim3(BATCH), dim3(128), 0, stream>>>(q, nk, nv, kc, vc, btab, ctx, ws);
    attn<<<dim3(NPART, NKVH, BATCH), dim3(256), 0, stream>>>(kc, vc, ctx, btab, ws);
    attn_reduce<<<dim3(BATCH * NH), dim3(128), 0, stream>>>(ctx, ws, out);
}